// Round 2
// baseline (649.418 us; speedup 1.0000x reference)
//
#include <hip/hip_runtime.h>
#include <hip/hip_cooperative_groups.h>

namespace cg = cooperative_groups;

// DQNet — MI355X (gfx950). Round-11: COOPERATIVE FUSION.
// Round-10 post-mortem: full fusion (64 blocks) = 10.7% occupancy, 13.8%
// VALUBusy -> latency-bound at 1/4 machine. Cost model across rounds:
//   total ~= 57us fixed + 41us unconditional ws-poison + kernel work.
// => workspace use is FREE; the lever is kernel work at full machine width.
// This round: 256 blocks x 1024 thr (4 blocks/group, 25 dst-rows each,
// 4 waves/SIMD on ALL 256 CUs), ONE cooperative launch, grid.sync() between
// GNN steps. Wt persists in LDS (no global round-trip), base persists in
// registers; only h (25.6KB/group) exchanged via global + device fences.
// Algebra (verified rounds 2-10):
//  - segment_sum over dense graph == n1 = Wt @ h, Wt[j][i]=e1^2*d, diag 0
//  - GNN step 1 has h=0  =>  h1 = relu(base + l2_b) exactly
//  - h2[a0]+h2[a1] == (h[a0]+h[a1])@t7_1_w + 2*t7_1_b
//  - t4 diag correction: -relu(t4_b) cancels spurious i==j term
#define HD 64
#define NPG 100
#define NGRP 64
#define NACT 50
#define EPG 9900

typedef const float* fcp;

__global__ __launch_bounds__(1024)
void k_coop(fcp label, fcp e_type, fcp dvec,
            fcp l1_w, fcp l1_b, fcp l2_w, fcp l2_b,
            fcp t3_w, fcp t3_b, fcp t4_w, fcp t4_b,
            fcp t5_w, fcp t5_b, fcp t6_w, fcp t6_b,
            fcp t7_1_w, fcp t7_1_b, fcp t7_2_w, fcp t7_2_b,
            fcp t9_1_w, fcp t9_1_b, fcp t9_2_w, fcp t9_2_b,
            const int* __restrict__ actions,
            float* __restrict__ hA, float* __restrict__ hB,
            float* __restrict__ out)
{
    cg::grid_group grid = cg::this_grid();
    const int g  = blockIdx.x >> 2;
    const int c  = blockIdx.x & 3;
    const int j0 = c * 25;
    const int t  = threadIdx.x;
    const int hh = t & 63;
    const int w  = t >> 6;              // wave 0..15 (wave-uniform)

    __shared__ __align__(16) float s_ld[2500];      // 10 KB  [jl*100+i] (s); tail: free
    __shared__ __align__(16) float w_ld[2500];      // 10 KB  [jl*100+i] (Wt); tail: ha/r1
    __shared__ __align__(16) float hs[NPG * HD];    // 25.6 KB full-group h slab
    __shared__ __align__(16) float t4s[25 * HD];    // 6.4 KB t4 sums, then n1
    __shared__ __align__(16) float awk[16 * HD];    // 4 KB mean partials
    __shared__ float gbuf[HD];

    // ---- prefetch (independent of staging; hides HBM latency) ----
    float l1r[5];
    #pragma unroll
    for (int kk = 0; kk < 5; ++kk) l1r[kk] = l1_w[kk * HD + hh];

    // rows owned by this thread: jl0 = w (always), jl1 = 16+w (w<9)
    float basev0 = 0.f, basev1 = 0.f;
    #pragma unroll
    for (int kk = 0; kk < 5; ++kk)
        basev0 += label[(g * NPG + j0 + w) * 5 + kk] * l1r[kk];
    if (w < 9) {
        #pragma unroll
        for (int kk = 0; kk < 5; ++kk)
            basev1 += label[(g * NPG + j0 + 16 + w) * 5 + kk] * l1r[kk];
    }

    const int acnt = (c < 2) ? 13 : 12;             // actions per block
    const int abase = c * 12 + (c < 2 ? c : 2);     // 0,13,26,38
    int a0r = 0, a1r = 0;
    if (w < acnt) {
        const int a = g * NACT + abase + w;
        a0r = actions[a * 2 + 0];
        a1r = actions[a * 2 + 1];
    }

    // ---- phase A: stage own 25-dst edge chunk -> s, Wt (coalesced in e) ----
    const float2* et2 = (const float2*)e_type;
    const int ebase = g * EPG;
    for (int idx = t; idx < 2500; idx += 1024) {
        const int i  = idx / 25;        // source node 0..99
        const int jl = idx - i * 25;
        const int j  = j0 + jl;
        float s = 0.f, wv = 0.f;
        if (i != j) {
            const int e = ebase + i * 99 + j - (j > i ? 1 : 0);
            const float e1 = et2[e].x;
            const float dd = dvec[e];
            s  = dd * e1;
            wv = e1 * e1 * dd;
        }
        s_ld[jl * 100 + i] = s;
        w_ld[jl * 100 + i] = wv;
    }
    __syncthreads();                                // B1: edges staged

    // ---- phase B: t4 row sums (wave-local rows, no further barrier) ----
    const float w4  = t4_w[hh];
    const float b4  = t4_b[hh];
    const float rb4 = fmaxf(b4, 0.f);
    {
        float a0 = 0.f, a1 = 0.f, a2 = 0.f, a3 = 0.f;
        #pragma unroll 5
        for (int ib = 0; ib < 25; ++ib) {
            const float4 s4 = *(const float4*)&s_ld[w * 100 + 4 * ib];
            a0 += fmaxf(s4.x * w4 + b4, 0.f);
            a1 += fmaxf(s4.y * w4 + b4, 0.f);
            a2 += fmaxf(s4.z * w4 + b4, 0.f);
            a3 += fmaxf(s4.w * w4 + b4, 0.f);
        }
        t4s[w * HD + hh] = (a0 + a1) + (a2 + a3) - rb4;
    }
    if (w < 9) {
        float a0 = 0.f, a1 = 0.f, a2 = 0.f, a3 = 0.f;
        #pragma unroll 5
        for (int ib = 0; ib < 25; ++ib) {
            const float4 s4 = *(const float4*)&s_ld[(16 + w) * 100 + 4 * ib];
            a0 += fmaxf(s4.x * w4 + b4, 0.f);
            a1 += fmaxf(s4.y * w4 + b4, 0.f);
            a2 += fmaxf(s4.z * w4 + b4, 0.f);
            a3 += fmaxf(s4.w * w4 + b4, 0.f);
        }
        t4s[(16 + w) * HD + hh] = (a0 + a1) + (a2 + a3) - rb4;
    }

    // ---- base = label@l1 + l1_b + t4s@t3 + t3_b (registers, persists) ----
    const float bb   = l1_b[hh] + t3_b[hh];
    const float l2bv = l2_b[hh];
    basev0 += bb; basev1 += bb;
    for (int ib = 0; ib < 16; ++ib) {               // q-outer weight loads
        const float tw0 = t3_w[(4 * ib + 0) * HD + hh];
        const float tw1 = t3_w[(4 * ib + 1) * HD + hh];
        const float tw2 = t3_w[(4 * ib + 2) * HD + hh];
        const float tw3 = t3_w[(4 * ib + 3) * HD + hh];
        const float4 x0 = *(const float4*)&t4s[w * HD + 4 * ib];
        basev0 += x0.x * tw0 + x0.y * tw1 + x0.z * tw2 + x0.w * tw3;
        if (w < 9) {
            const float4 x1 = *(const float4*)&t4s[(16 + w) * HD + 4 * ib];
            basev1 += x1.x * tw0 + x1.y * tw1 + x1.z * tw2 + x1.w * tw3;
        }
    }
    // GNN step 1 (h0=0): h1 = relu(base + l2_b) -> global
    hA[(g * NPG + j0 + w) * HD + hh] = fmaxf(basev0 + l2bv, 0.f);
    if (w < 9)
        hA[(g * NPG + j0 + 16 + w) * HD + hh] = fmaxf(basev1 + l2bv, 0.f);
    __threadfence();
    grid.sync();                                    // S1: h1 visible

    // ---- GNN steps 2,3: n1 = Wt@h (Wt in LDS), h' = relu(base+n1@l2+l2_b) --
    #pragma unroll 1
    for (int step = 0; step < 2; ++step) {
        fcp    hin  = step ? (fcp)hB : (fcp)hA;
        float* hout = step ? hA : hB;
        {   // stage full group slab (float4, coalesced; L2/L3-resident)
            const float4* hin4 = (const float4*)(hin + g * NPG * HD);
            float4* hs4 = (float4*)hs;
            for (int idx = t; idx < NPG * HD / 4; idx += 1024) hs4[idx] = hin4[idx];
        }
        __syncthreads();                            // slab ready

        float acc0 = 0.f, acc1 = 0.f;
        for (int ib = 0; ib < 25; ++ib) {
            const float h0 = hs[(4 * ib + 0) * HD + hh];
            const float h1 = hs[(4 * ib + 1) * HD + hh];
            const float h2 = hs[(4 * ib + 2) * HD + hh];
            const float h3 = hs[(4 * ib + 3) * HD + hh];
            const float4 wa = *(const float4*)&w_ld[w * 100 + 4 * ib];
            acc0 += wa.x * h0 + wa.y * h1 + wa.z * h2 + wa.w * h3;
            if (w < 9) {
                const float4 wb = *(const float4*)&w_ld[(16 + w) * 100 + 4 * ib];
                acc1 += wb.x * h0 + wb.y * h1 + wb.z * h2 + wb.w * h3;
            }
        }
        t4s[w * HD + hh] = acc0;                    // n1, wave-local rows
        if (w < 9) t4s[(16 + w) * HD + hh] = acc1;
        // no barrier: l2 matvec reads only this wave's own n1 rows

        float v0 = basev0 + l2bv, v1 = basev1 + l2bv;
        for (int ib = 0; ib < 16; ++ib) {
            const float w0 = l2_w[(4 * ib + 0) * HD + hh];
            const float w1 = l2_w[(4 * ib + 1) * HD + hh];
            const float w2 = l2_w[(4 * ib + 2) * HD + hh];
            const float w3 = l2_w[(4 * ib + 3) * HD + hh];
            const float4 x0 = *(const float4*)&t4s[w * HD + 4 * ib];
            v0 += x0.x * w0 + x0.y * w1 + x0.z * w2 + x0.w * w3;
            if (w < 9) {
                const float4 x1 = *(const float4*)&t4s[(16 + w) * HD + 4 * ib];
                v1 += x1.x * w0 + x1.y * w1 + x1.z * w2 + x1.w * w3;
            }
        }
        hout[(g * NPG + j0 + w) * HD + hh] = fmaxf(v0, 0.f);
        if (w < 9)
            hout[(g * NPG + j0 + 16 + w) * HD + hh] = fmaxf(v1, 0.f);
        __threadfence();
        grid.sync();                                // S2/S3: h' visible
    }

    // ---- tail: final h in hA. Stage slab, stem + own 12-13 actions ----
    {
        const float4* hin4 = (const float4*)(hA + g * NPG * HD);
        float4* hs4 = (float4*)hs;
        for (int idx = t; idx < NPG * HD / 4; idx += 1024) hs4[idx] = hin4[idx];
    }
    __syncthreads();                                // slab ready

    {   // mean partials (all 16 waves)
        float ml = 0.f;
        for (int j = w; j < NPG; j += 16) ml += hs[j * HD + hh];
        awk[w * HD + hh] = ml;
    }
    float* hsum = w_ld;                             // Wt dead; reuse for ha/r2
    float* r1s  = w_ld + 1024;
    if (w < acnt)                                   // ha = h[a0]+h[a1]
        hsum[w * HD + hh] = hs[a0r * HD + hh] + hs[a1r * HD + hh];
    __syncthreads();                                // awk ready for wave 15

    if (w == 15) {   // stem chain (redundant per block), concurrent w/ actions
        float ml = 0.f;
        #pragma unroll
        for (int ww = 0; ww < 16; ++ww) ml += awk[ww * HD + hh];
        ml *= (1.f / NPG);
        float s = t6_b[hh];
        #pragma unroll 8
        for (int q = 0; q < HD; ++q) s += __shfl(ml, q, 64) * t6_w[q * HD + hh];
        s = fmaxf(s, 0.f);
        float gb = t9_1_b[hh];
        #pragma unroll 8
        for (int q = 0; q < HD; ++q) gb += __shfl(s, q, 64) * t9_1_w[q * HD + hh];
        gbuf[hh] = gb;
    } else if (w < acnt) {
        // r1 = relu(ha @ t7_1_w + 2*b71)   (one action row per wave)
        float r = 2.f * t7_1_b[hh];
        for (int ib = 0; ib < 16; ++ib) {
            const float w0 = t7_1_w[(4 * ib + 0) * HD + hh];
            const float w1 = t7_1_w[(4 * ib + 1) * HD + hh];
            const float w2 = t7_1_w[(4 * ib + 2) * HD + hh];
            const float w3 = t7_1_w[(4 * ib + 3) * HD + hh];
            const float4 x4 = *(const float4*)&hsum[w * HD + 4 * ib];
            r += x4.x * w0 + x4.y * w1 + x4.z * w2 + x4.w * w3;
        }
        r1s[w * HD + hh] = fmaxf(r, 0.f);
        // r2 = relu(r1 @ t7_2_w + b72) -> back into hsum (same wave row)
        float r2 = t7_2_b[hh];
        for (int ib = 0; ib < 16; ++ib) {
            const float w0 = t7_2_w[(4 * ib + 0) * HD + hh];
            const float w1 = t7_2_w[(4 * ib + 1) * HD + hh];
            const float w2 = t7_2_w[(4 * ib + 2) * HD + hh];
            const float w3 = t7_2_w[(4 * ib + 3) * HD + hh];
            const float4 x4 = *(const float4*)&r1s[w * HD + 4 * ib];
            r2 += x4.x * w0 + x4.y * w1 + x4.z * w2 + x4.w * w3;
        }
        hsum[w * HD + hh] = fmaxf(r2, 0.f);
    }
    __syncthreads();                                // gbuf ready

    if (w < acnt) {
        // u = r2 @ t9_2_w + b92 ; q = relu(gb+u) ; Q = q . t5_w + t5_b
        float u = t9_2_b[hh];
        for (int ib = 0; ib < 16; ++ib) {
            const float w0 = t9_2_w[(4 * ib + 0) * HD + hh];
            const float w1 = t9_2_w[(4 * ib + 1) * HD + hh];
            const float w2 = t9_2_w[(4 * ib + 2) * HD + hh];
            const float w3 = t9_2_w[(4 * ib + 3) * HD + hh];
            const float4 x4 = *(const float4*)&hsum[w * HD + 4 * ib];
            u += x4.x * w0 + x4.y * w1 + x4.z * w2 + x4.w * w3;
        }
        float qv = fmaxf(gbuf[hh] + u, 0.f) * t5_w[hh];
        #pragma unroll
        for (int off = 32; off > 0; off >>= 1) qv += __shfl_xor(qv, off, 64);
        if (hh == 0) out[g * NACT + abase + w] = qv + t5_b[0];
    }
}

// ---------------------------------------------------------------------------
extern "C" void kernel_launch(void* const* d_in, const int* in_sizes, int n_in,
                              void* d_out, int out_size, void* d_ws, size_t ws_size,
                              hipStream_t stream)
{
    fcp label  = (fcp)d_in[0];
    fcp e_type = (fcp)d_in[1];
    fcp dvec   = (fcp)d_in[2];
    fcp l1_w   = (fcp)d_in[3];
    fcp l1_b   = (fcp)d_in[4];
    fcp l2_w   = (fcp)d_in[5];
    fcp l2_b   = (fcp)d_in[6];
    fcp t3_w   = (fcp)d_in[7];
    fcp t3_b   = (fcp)d_in[8];
    fcp t4_w   = (fcp)d_in[9];
    fcp t4_b   = (fcp)d_in[10];
    fcp t5_w   = (fcp)d_in[11];
    fcp t5_b   = (fcp)d_in[12];
    fcp t6_w   = (fcp)d_in[13];
    fcp t6_b   = (fcp)d_in[14];
    fcp t7_1_w = (fcp)d_in[15];
    fcp t7_1_b = (fcp)d_in[16];
    fcp t7_2_w = (fcp)d_in[17];
    fcp t7_2_b = (fcp)d_in[18];
    fcp t9_1_w = (fcp)d_in[19];
    fcp t9_1_b = (fcp)d_in[20];
    fcp t9_2_w = (fcp)d_in[21];
    fcp t9_2_b = (fcp)d_in[22];
    // d_in[23]=src, d_in[24]=dst -- topology derived analytically
    const int* actions = (const int*)d_in[25];
    float* outp = (float*)d_out;

    // h ping-pong buffers in workspace (poison fill is unconditional => free)
    float* hA = (float*)d_ws;
    float* hB = (float*)((char*)d_ws + 1638400);

    void* args[] = {
        (void*)&label, (void*)&e_type, (void*)&dvec,
        (void*)&l1_w, (void*)&l1_b, (void*)&l2_w, (void*)&l2_b,
        (void*)&t3_w, (void*)&t3_b, (void*)&t4_w, (void*)&t4_b,
        (void*)&t5_w, (void*)&t5_b, (void*)&t6_w, (void*)&t6_b,
        (void*)&t7_1_w, (void*)&t7_1_b, (void*)&t7_2_w, (void*)&t7_2_b,
        (void*)&t9_1_w, (void*)&t9_1_b, (void*)&t9_2_w, (void*)&t9_2_b,
        (void*)&actions, (void*)&hA, (void*)&hB, (void*)&outp
    };
    hipError_t err = hipLaunchCooperativeKernel(
        (const void*)k_coop, dim3(NGRP * 4), dim3(1024), args, 0, stream);
    if (err != hipSuccess) {
        // Fallback: plain launch. 256 blocks @ 56KB LDS / 1024 thr have 2x
        // residency margin on 256 CUs, so the grid barrier still converges.
        k_coop<<<dim3(NGRP * 4), dim3(1024), 0, stream>>>(
            label, e_type, dvec, l1_w, l1_b, l2_w, l2_b, t3_w, t3_b,
            t4_w, t4_b, t5_w, t5_b, t6_w, t6_b, t7_1_w, t7_1_b,
            t7_2_w, t7_2_b, t9_1_w, t9_1_b, t9_2_w, t9_2_b,
            actions, hA, hB, outp);
    }
}

// Round 3
// 171.055 us; speedup vs baseline: 3.7965x; 3.7965x over previous
//
#include <hip/hip_runtime.h>

// DQNet — MI355X (gfx950). Round-12: round-9 structure + occupancy doubling.
// Round-11 post-mortem: cooperative grid.sync on gfx950 = 0.5 GB coherence
// traffic (L2 writeback/inv per sync) -> 460us. DEAD END, reverted.
// Round-10 showed ~55% per-CU VALUBusy at 4 waves/SIMD; round-9 kernels ran
// at 2 waves/SIMD (512thr, 1 block/CU). This round keeps the proven 4-launch
// split and doubles resident waves per SIMD in every kernel:
//   K1: 256 x 1024thr (16 waves/CU);  K2: 512 x 512thr (2 blocks/CU);
//   K3: 256 x 512thr (2 blocks/CU).
// Algebra (verified rounds 2-10):
//  - segment_sum over dense graph == n1 = Wt @ h, Wt[j][i]=e1^2*d, diag 0
//  - GNN step 1 has h=0  =>  h1 = relu(base + l2_b) exactly
//  - h2[a0]+h2[a1] == (h[a0]+h[a1])@t7_1_w + 2*t7_1_b
//  - t4 diag correction: -relu(t4_b) cancels spurious i==j term
#define HD 64
#define NPG 100
#define NGRP 64
#define NACT 50
#define EPG 9900

typedef const float* fcp;

// ---------------------------------------------------------------------------
// K1: block = (group, 25-dst chunk), grid 256, 1024 thr (4 waves/SIMD).
// edges -> Wt (global) + t4 sums -> base + h1.  ONE barrier.
// Rows per wave: jl = w and 16+w (w<9).
// ---------------------------------------------------------------------------
__global__ __launch_bounds__(1024)
void k_edge_base(fcp label, fcp e_type, fcp dvec,
                 fcp l1_w, fcp l1_b, fcp l2_b,
                 fcp t3_w, fcp t3_b, fcp t4_w, fcp t4_b,
                 float* __restrict__ Wt, float* __restrict__ baseo,
                 float* __restrict__ hA)
{
    const int g  = blockIdx.x >> 2;
    const int c  = blockIdx.x & 3;
    const int j0 = c * 25;
    const int t  = threadIdx.x;
    const int hh = t & 63;
    const int w  = t >> 6;          // wave 0..15

    __shared__ __align__(16) float s_ld[2500];      // [jl*100 + i]
    __shared__ __align__(16) float w_ld[2500];
    __shared__ __align__(16) float t4s[25 * HD];

    // prefetch label rows + l1_w (independent of staging; hides HBM latency)
    float l1r[5], lab0[5], lab1[5];
    #pragma unroll
    for (int kk = 0; kk < 5; ++kk) l1r[kk] = l1_w[kk * HD + hh];
    #pragma unroll
    for (int kk = 0; kk < 5; ++kk)
        lab0[kk] = label[(g * NPG + j0 + w) * 5 + kk];
    #pragma unroll
    for (int kk = 0; kk < 5; ++kk)
        lab1[kk] = (w < 9) ? label[(g * NPG + j0 + 16 + w) * 5 + kk] : 0.f;

    const float2* et2 = (const float2*)e_type;
    const int ebase = g * EPG;
    // coalesced edge staging (consecutive t -> consecutive e), LDS transpose
    for (int idx = t; idx < 2500; idx += 1024) {
        const int i  = idx / 25;
        const int jl = idx - i * 25;
        const int j  = j0 + jl;
        float s = 0.f, wv = 0.f;
        if (i != j) {
            const int e = ebase + i * 99 + j - (j > i ? 1 : 0);
            const float e1 = et2[e].x;
            const float dd = dvec[e];
            s  = dd * e1;
            wv = e1 * e1 * dd;
        }
        s_ld[jl * 100 + i] = s;
        w_ld[jl * 100 + i] = wv;
    }
    __syncthreads();        // the only barrier in K1

    {   // Wt global write: coalesced copy
        float* wd = Wt + g * (NPG * NPG) + j0 * NPG;
        for (int idx = t; idx < 2500; idx += 1024) wd[idx] = w_ld[idx];
    }

    // t4 sums — wave-local rows (jl = w, 16+w), float4 reads, 4 partial accs
    const float w4  = t4_w[hh];
    const float b4  = t4_b[hh];
    const float rb4 = fmaxf(b4, 0.f);
    {
        float a0 = 0.f, a1 = 0.f, a2 = 0.f, a3 = 0.f;
        #pragma unroll 5
        for (int ib = 0; ib < 25; ++ib) {
            const float4 s4 = *(const float4*)&s_ld[w * 100 + 4 * ib];
            a0 += fmaxf(s4.x * w4 + b4, 0.f);
            a1 += fmaxf(s4.y * w4 + b4, 0.f);
            a2 += fmaxf(s4.z * w4 + b4, 0.f);
            a3 += fmaxf(s4.w * w4 + b4, 0.f);
        }
        t4s[w * HD + hh] = (a0 + a1) + (a2 + a3) - rb4;
    }
    if (w < 9) {
        float a0 = 0.f, a1 = 0.f, a2 = 0.f, a3 = 0.f;
        #pragma unroll 5
        for (int ib = 0; ib < 25; ++ib) {
            const float4 s4 = *(const float4*)&s_ld[(16 + w) * 100 + 4 * ib];
            a0 += fmaxf(s4.x * w4 + b4, 0.f);
            a1 += fmaxf(s4.y * w4 + b4, 0.f);
            a2 += fmaxf(s4.z * w4 + b4, 0.f);
            a3 += fmaxf(s4.w * w4 + b4, 0.f);
        }
        t4s[(16 + w) * HD + hh] = (a0 + a1) + (a2 + a3) - rb4;
    }
    // no barrier: base matmul reads only this wave's own t4s rows

    const float bb   = l1_b[hh] + t3_b[hh];
    const float l2bv = l2_b[hh];
    float v0 = bb, v1 = bb;
    #pragma unroll
    for (int kk = 0; kk < 5; ++kk) v0 += lab0[kk] * l1r[kk];
    #pragma unroll
    for (int kk = 0; kk < 5; ++kk) v1 += lab1[kk] * l1r[kk];
    for (int ib = 0; ib < 16; ++ib) {       // q-outer: weight loads shared
        const float tw0 = t3_w[(4 * ib + 0) * HD + hh];
        const float tw1 = t3_w[(4 * ib + 1) * HD + hh];
        const float tw2 = t3_w[(4 * ib + 2) * HD + hh];
        const float tw3 = t3_w[(4 * ib + 3) * HD + hh];
        const float4 x0 = *(const float4*)&t4s[w * HD + 4 * ib];
        v0 += x0.x * tw0 + x0.y * tw1 + x0.z * tw2 + x0.w * tw3;
        if (w < 9) {
            const float4 x1 = *(const float4*)&t4s[(16 + w) * HD + 4 * ib];
            v1 += x1.x * tw0 + x1.y * tw1 + x1.z * tw2 + x1.w * tw3;
        }
    }
    {
        const int n = g * NPG + j0 + w;
        baseo[n * HD + hh] = v0;
        hA[n * HD + hh]    = fmaxf(v0 + l2bv, 0.f);   // GNN step 1 (h0=0)
    }
    if (w < 9) {
        const int n = g * NPG + j0 + 16 + w;
        baseo[n * HD + hh] = v1;
        hA[n * HD + hh]    = fmaxf(v1 + l2bv, 0.f);
    }
}

// ---------------------------------------------------------------------------
// K2: one GNN step. block = (group, 12/13-dst chunk), grid 512, 512 thr.
// 2 blocks/CU (LDS 34KB) -> 16 waves/CU. ONE barrier.
// Chunks: c<4: j0=13c cnt=13 ; c>=4: j0=52+12(c-4) cnt=12.
// Rows per wave: jl = w (always) and 8+w (if 8+w < cnt).
// ---------------------------------------------------------------------------
__global__ __launch_bounds__(512)
void k_gnn_step(const float* __restrict__ Wt, const float* __restrict__ baseo,
                const float* __restrict__ h_old, fcp l2_w, fcp l2_b,
                float* __restrict__ h_new)
{
    const int g   = blockIdx.x >> 3;
    const int c   = blockIdx.x & 7;
    const int cnt = (c < 4) ? 13 : 12;
    const int j0  = (c < 4) ? 13 * c : 52 + 12 * (c - 4);
    const int t   = threadIdx.x;
    const int hh  = t & 63;
    const int w   = t >> 6;         // wave 0..7
    const bool r1ok = (8 + w) < cnt;

    __shared__ __align__(16) float hs[NPG * HD];    // 25.6 KB
    __shared__ __align__(16) float wr[13 * NPG];    // 5.2 KB [jl*100 + i]
    __shared__ __align__(16) float n1s[13 * HD];    // 3.3 KB

    // prefetch base rows (hides HBM latency behind staging)
    const float l2bv = l2_b[hh];
    const float bs0 = baseo[(g * NPG + j0 + w) * HD + hh];
    const float bs1 = r1ok ? baseo[(g * NPG + j0 + 8 + w) * HD + hh] : 0.f;

    {   // stage h slab (float4) + Wt chunk, coalesced
        const float4* ho4 = (const float4*)(h_old + g * NPG * HD);
        float4* hs4 = (float4*)hs;
        for (int idx = t; idx < NPG * HD / 4; idx += 512) hs4[idx] = ho4[idx];
        const float* wsrc = Wt + g * (NPG * NPG) + j0 * NPG;
        for (int idx = t; idx < cnt * NPG; idx += 512) wr[idx] = wsrc[idx];
    }
    __syncthreads();        // the only barrier in K2

    // phase 1: n1[jl][hh] = sum_i Wt[jl][i] * h[i][hh]   (wave-local rows)
    float acc0 = 0.f, acc1 = 0.f;
    for (int ib = 0; ib < 25; ++ib) {
        const float h0 = hs[(4 * ib + 0) * HD + hh];
        const float h1 = hs[(4 * ib + 1) * HD + hh];
        const float h2 = hs[(4 * ib + 2) * HD + hh];
        const float h3 = hs[(4 * ib + 3) * HD + hh];
        const float4 wa = *(const float4*)&wr[w * 100 + 4 * ib];
        acc0 += wa.x * h0 + wa.y * h1 + wa.z * h2 + wa.w * h3;
        if (r1ok) {
            const float4 wb = *(const float4*)&wr[(8 + w) * 100 + 4 * ib];
            acc1 += wb.x * h0 + wb.y * h1 + wb.z * h2 + wb.w * h3;
        }
    }
    n1s[w * HD + hh] = acc0;
    if (r1ok) n1s[(8 + w) * HD + hh] = acc1;
    // no barrier: phase 2 reads only this wave's own n1s rows

    float v0 = bs0 + l2bv, v1 = bs1 + l2bv;
    for (int ib = 0; ib < 16; ++ib) {
        const float w0 = l2_w[(4 * ib + 0) * HD + hh];
        const float w1 = l2_w[(4 * ib + 1) * HD + hh];
        const float w2 = l2_w[(4 * ib + 2) * HD + hh];
        const float w3 = l2_w[(4 * ib + 3) * HD + hh];
        const float4 x0 = *(const float4*)&n1s[w * HD + 4 * ib];
        v0 += x0.x * w0 + x0.y * w1 + x0.z * w2 + x0.w * w3;
        if (r1ok) {
            const float4 x1 = *(const float4*)&n1s[(8 + w) * HD + 4 * ib];
            v1 += x1.x * w0 + x1.y * w1 + x1.z * w2 + x1.w * w3;
        }
    }
    h_new[(g * NPG + j0 + w) * HD + hh] = fmaxf(v0, 0.f);
    if (r1ok)
        h_new[(g * NPG + j0 + 8 + w) * HD + hh] = fmaxf(v1, 0.f);
}

// ---------------------------------------------------------------------------
// K3: tail. block = (group, 12/13-action chunk), grid 256, 512 thr.
// 2 blocks/CU. Waves 0-6: action rows al = aw + 7m (m<2). Wave 7: stem chain.
// ---------------------------------------------------------------------------
__global__ __launch_bounds__(512)
void k_tail(const float* __restrict__ hfin, const int* __restrict__ actions,
            fcp t5_w, fcp t5_b, fcp t6_w, fcp t6_b,
            fcp t7_1_w, fcp t7_1_b, fcp t7_2_w, fcp t7_2_b,
            fcp t9_1_w, fcp t9_1_b, fcp t9_2_w, fcp t9_2_b,
            float* __restrict__ out)
{
    const int g     = blockIdx.x >> 2;
    const int c     = blockIdx.x & 3;
    const int acnt  = (c < 2) ? 13 : 12;
    const int abase = c * 12 + (c < 2 ? c : 2);     // 0,13,26,38
    const int t     = threadIdx.x;
    const int hh    = t & 63;
    const int aw    = t >> 6;       // wave 0..7

    __shared__ __align__(16) float hsb[NPG * HD];   // 25.6 KB
    __shared__ __align__(16) float hsum[13 * HD];   // ha -> r2 (wave-local)
    __shared__ __align__(16) float r1s[13 * HD];
    __shared__ __align__(16) float awk[8 * HD];     // mean partials
    __shared__ float gbuf[HD];

    // prefetch action indices (hides latency behind staging)
    int a0r[2], a1r[2];
    #pragma unroll
    for (int m = 0; m < 2; ++m) {
        const int al = aw + 7 * m;
        a0r[m] = 0; a1r[m] = 0;
        if (aw < 7 && al < acnt) {
            const int a = g * NACT + abase + al;
            a0r[m] = actions[a * 2 + 0];
            a1r[m] = actions[a * 2 + 1];
        }
    }

    {   // stage h slab (float4, coalesced)
        const float4* hg4 = (const float4*)(hfin + g * NPG * HD);
        float4* hs4 = (float4*)hsb;
        for (int idx = t; idx < NPG * HD / 4; idx += 512) hs4[idx] = hg4[idx];
    }
    __syncthreads();                        // barrier 1: hsb staged

    {   // mean partials (all 8 waves)
        float m = 0.f;
        for (int j = aw; j < NPG; j += 8) m += hsb[j * HD + hh];
        awk[aw * HD + hh] = m;
    }
    // ha = h[a0]+h[a1] (wave-local rows; hsb read-only from here)
    #pragma unroll
    for (int m = 0; m < 2; ++m) {
        const int al = aw + 7 * m;
        if (aw < 7 && al < acnt)
            hsum[al * HD + hh] = hsb[a0r[m] * HD + hh] + hsb[a1r[m] * HD + hh];
    }
    __syncthreads();                        // barrier 2: awk ready for wave 7

    if (aw == 7) {   // stem chain (redundant per block), concurrent w/ actions
        float ml = 0.f;
        #pragma unroll
        for (int ww = 0; ww < 8; ++ww) ml += awk[ww * HD + hh];
        ml *= (1.f / NPG);
        float s = t6_b[hh];
        #pragma unroll 8
        for (int q = 0; q < HD; ++q) s += __shfl(ml, q, 64) * t6_w[q * HD + hh];
        s = fmaxf(s, 0.f);
        float gb = t9_1_b[hh];
        #pragma unroll 8
        for (int q = 0; q < HD; ++q) gb += __shfl(s, q, 64) * t9_1_w[q * HD + hh];
        gbuf[hh] = gb;
    } else {
        // r1 = relu(ha @ t7_1_w + 2*b71)   (wave-local rows, q-outer weights)
        const float b71 = 2.f * t7_1_b[hh];
        float r[2];
        r[0] = b71; r[1] = b71;
        for (int ib = 0; ib < 16; ++ib) {
            const float w0 = t7_1_w[(4 * ib + 0) * HD + hh];
            const float w1 = t7_1_w[(4 * ib + 1) * HD + hh];
            const float w2 = t7_1_w[(4 * ib + 2) * HD + hh];
            const float w3 = t7_1_w[(4 * ib + 3) * HD + hh];
            #pragma unroll
            for (int m = 0; m < 2; ++m) {
                const int al = aw + 7 * m;
                if (al < acnt) {
                    const float4 x4 = *(const float4*)&hsum[al * HD + 4 * ib];
                    r[m] += x4.x * w0 + x4.y * w1 + x4.z * w2 + x4.w * w3;
                }
            }
        }
        #pragma unroll
        for (int m = 0; m < 2; ++m) {
            const int al = aw + 7 * m;
            if (al < acnt) r1s[al * HD + hh] = fmaxf(r[m], 0.f);
        }
        // r2 = relu(r1 @ t7_2_w + b72) -> hsum (same wave-local rows)
        const float b72 = t7_2_b[hh];
        r[0] = b72; r[1] = b72;
        for (int ib = 0; ib < 16; ++ib) {
            const float w0 = t7_2_w[(4 * ib + 0) * HD + hh];
            const float w1 = t7_2_w[(4 * ib + 1) * HD + hh];
            const float w2 = t7_2_w[(4 * ib + 2) * HD + hh];
            const float w3 = t7_2_w[(4 * ib + 3) * HD + hh];
            #pragma unroll
            for (int m = 0; m < 2; ++m) {
                const int al = aw + 7 * m;
                if (al < acnt) {
                    const float4 x4 = *(const float4*)&r1s[al * HD + 4 * ib];
                    r[m] += x4.x * w0 + x4.y * w1 + x4.z * w2 + x4.w * w3;
                }
            }
        }
        #pragma unroll
        for (int m = 0; m < 2; ++m) {
            const int al = aw + 7 * m;
            if (al < acnt) hsum[al * HD + hh] = fmaxf(r[m], 0.f);
        }
    }
    __syncthreads();                        // barrier 3: gbuf ready

    if (aw < 7) {
        // u = r2 @ t9_2_w + b92 ; q = relu(gb+u) ; Q = q . t5_w + t5_b
        const float b92  = t9_2_b[hh];
        const float t5wv = t5_w[hh];
        const float t5bv = t5_b[0];
        const float gbv  = gbuf[hh];
        float u[2];
        u[0] = b92; u[1] = b92;
        for (int ib = 0; ib < 16; ++ib) {
            const float w0 = t9_2_w[(4 * ib + 0) * HD + hh];
            const float w1 = t9_2_w[(4 * ib + 1) * HD + hh];
            const float w2 = t9_2_w[(4 * ib + 2) * HD + hh];
            const float w3 = t9_2_w[(4 * ib + 3) * HD + hh];
            #pragma unroll
            for (int m = 0; m < 2; ++m) {
                const int al = aw + 7 * m;
                if (al < acnt) {
                    const float4 x4 = *(const float4*)&hsum[al * HD + 4 * ib];
                    u[m] += x4.x * w0 + x4.y * w1 + x4.z * w2 + x4.w * w3;
                }
            }
        }
        #pragma unroll
        for (int m = 0; m < 2; ++m) {
            const int al = aw + 7 * m;
            float qv = fmaxf(gbv + u[m], 0.f) * t5wv;
            #pragma unroll
            for (int off = 32; off > 0; off >>= 1) qv += __shfl_xor(qv, off, 64);
            if (al < acnt && hh == 0) out[g * NACT + abase + al] = qv + t5bv;
        }
    }
}

// ---------------------------------------------------------------------------
extern "C" void kernel_launch(void* const* d_in, const int* in_sizes, int n_in,
                              void* d_out, int out_size, void* d_ws, size_t ws_size,
                              hipStream_t stream)
{
    fcp label  = (fcp)d_in[0];
    fcp e_type = (fcp)d_in[1];
    fcp dvec   = (fcp)d_in[2];
    fcp l1_w   = (fcp)d_in[3];
    fcp l1_b   = (fcp)d_in[4];
    fcp l2_w   = (fcp)d_in[5];
    fcp l2_b   = (fcp)d_in[6];
    fcp t3_w   = (fcp)d_in[7];
    fcp t3_b   = (fcp)d_in[8];
    fcp t4_w   = (fcp)d_in[9];
    fcp t4_b   = (fcp)d_in[10];
    fcp t5_w   = (fcp)d_in[11];
    fcp t5_b   = (fcp)d_in[12];
    fcp t6_w   = (fcp)d_in[13];
    fcp t6_b   = (fcp)d_in[14];
    fcp t7_1_w = (fcp)d_in[15];
    fcp t7_1_b = (fcp)d_in[16];
    fcp t7_2_w = (fcp)d_in[17];
    fcp t7_2_b = (fcp)d_in[18];
    fcp t9_1_w = (fcp)d_in[19];
    fcp t9_1_b = (fcp)d_in[20];
    fcp t9_2_w = (fcp)d_in[21];
    fcp t9_2_b = (fcp)d_in[22];
    // d_in[23]=src, d_in[24]=dst -- topology derived analytically
    const int* actions = (const int*)d_in[25];

    // Workspace: Wt 2,560,000 B | base 1,638,400 | hA 1,638,400 | hB 1,638,400
    char* ws = (char*)d_ws;
    float* Wt   = (float*)(ws);
    float* base = (float*)(ws + 2560000);
    float* hA   = (float*)(ws + 2560000 + 1638400);
    float* hB   = (float*)(ws + 2560000 + 2 * 1638400);

    k_edge_base<<<dim3(NGRP * 4), dim3(1024), 0, stream>>>(
        label, e_type, dvec, l1_w, l1_b, l2_b, t3_w, t3_b, t4_w, t4_b,
        Wt, base, hA);
    k_gnn_step<<<dim3(NGRP * 8), dim3(512), 0, stream>>>(Wt, base, hA, l2_w, l2_b, hB);
    k_gnn_step<<<dim3(NGRP * 8), dim3(512), 0, stream>>>(Wt, base, hB, l2_w, l2_b, hA);
    k_tail<<<dim3(NGRP * 4), dim3(512), 0, stream>>>(
        hA, actions, t5_w, t5_b, t6_w, t6_b, t7_1_w, t7_1_b, t7_2_w, t7_2_b,
        t9_1_w, t9_1_b, t9_2_w, t9_2_b, (float*)d_out);
}